// Round 11
// baseline (151.151 us; speedup 1.0000x reference)
//
#include <hip/hip_runtime.h>

#define EMB 64
#define DICT 512
#define HW 4096              // 64*64
#define NPTS (32 * HW)       // 131072
#define MOM 0.99f
#define OMOM 0.01f
#define EPSV 1e-5f

typedef float v4f __attribute__((ext_vector_type(4)));
typedef unsigned int uint;
typedef uint uint4v __attribute__((ext_vector_type(4)));
typedef short short8 __attribute__((ext_vector_type(8)));
typedef __bf16 bf16x8 __attribute__((ext_vector_type(8)));
typedef float f32x4 __attribute__((ext_vector_type(4)));

// ws layout (dword offsets)
#define WS_COMMIT 0
#define WS_COUNTS 64                      // 512
#define WS_ESUM   1024                    // 64*512
#define WS_ZERO_FLOATS 33792              // zeroed by vq_prep each call
#define WS_EE     33792                   // 512 (fp32 ||e||^2)
#define WS_EHG    34320                   // 4 tiles * 4160 (packed bf16-hi E)
#define WS_IDS    67600                   // 131072 ints (natural pixel order)

#define PS 520      // plane stride in dwords: 130 rows x 4 dwords
#define TB 4160     // E tile blob: 8 planes (kh*4+g)

__device__ __forceinline__ uint bf16rne(float x) {
    uint u = __float_as_uint(x);
    return (u + 0x7fffu + ((u >> 16) & 1u)) >> 16;
}

__device__ __forceinline__ bf16x8 ldfragg(const uint* s, int idx) {
    return __builtin_bit_cast(bf16x8, *(const short8*)(s + idx));
}

// ------------------------------------------------- prep: zero ws + pack E-hi + ||e||^2
// 32 blocks x 256; block = 16 codes. Also grid-stride zeroes accumulators.
__global__ __launch_bounds__(256) void vq_prep(const float* __restrict__ embed,
                                               float* __restrict__ ws,
                                               uint* __restrict__ ehg,
                                               float* __restrict__ ee) {
    int t = threadIdx.x;
    int blk = blockIdx.x;
    for (int i = blk * 256 + t; i < WS_ZERO_FLOATS; i += 32 * 256) ws[i] = 0.f;

    int jl = t >> 4;           // 0..15
    int ci = t & 15;
    int j  = blk * 16 + jl;
    float nrm = 0.f;
    #pragma unroll
    for (int it = 0; it < 2; ++it) {
        int c2 = ci + it * 16;
        float x0 = embed[j * 64 + 2 * c2];
        float x1 = embed[j * 64 + 2 * c2 + 1];
        nrm = fmaf(x0, x0, nrm);
        nrm = fmaf(x1, x1, nrm);
        uint h0 = bf16rne(x0), h1 = bf16rne(x1);
        int plane = (c2 >> 4) * 4 + ((c2 >> 2) & 3);
        int idx = (j >> 7) * TB + plane * PS + (j & 127) * 4 + (c2 & 3);
        ehg[idx] = h0 | (h1 << 16);
    }
    #pragma unroll
    for (int off = 8; off > 0; off >>= 1) nrm += __shfl_xor(nrm, off, 16);
    if (ci == 0) ee[j] = nrm;
}

// ------------------------------------------------- MFMA argmax + exact rescore
// block: 128 points, 4 waves. Hi-only bf16 MFMA (error ~0.05) + per-lane top-2
// + 16-lane merge + exact fp32 rescore of 2 candidates. X in LDS as fp32.
__global__ __launch_bounds__(256, 4) void vq_argmax(
    const float* __restrict__ input, const uint* __restrict__ ehg,
    const float* __restrict__ ee, const float* __restrict__ embed,
    float* __restrict__ out_q, float* __restrict__ out_ids,
    int* __restrict__ ws_ids, float* __restrict__ ws) {
    __shared__ float sX[16 * PS];      // fp32: [plane=ch>>2][point][ch&3]
    __shared__ float sEE[512];
    __shared__ int sCand[256];
    __shared__ float sRes[256];
    __shared__ float cred[4];

    int t = threadIdx.x;
    int blk = blockIdx.x;
    int b = blk >> 5, h2 = blk & 31;

    // ---- stage X (fp32, no conversion) ----
    {
        int p = t & 127;
        const float* xg = input + (size_t)b * (EMB * HW) + h2 * 128 + p;
        int ch0 = (t >> 7) * 32;
        #pragma unroll
        for (int i = 0; i < 32; ++i) {
            int ch = ch0 + i;
            sX[(ch >> 2) * PS + p * 4 + (ch & 3)] = xg[(size_t)ch * HW];
        }
        sEE[t] = ee[t];
        sEE[t + 256] = ee[t + 256];
    }
    __syncthreads();

    int l = t & 63, wv = t >> 6;
    int g = l >> 4, col = l & 15;

    // A fragments (bf16-hi of X), built once. Fragment (mt,kh): channels
    // [kh*32+g*8, +8) of row wv*32+mt*16+col; dword v = pack(ch0+2v, ch0+2v+1).
    bf16x8 Ah[2][2];
    #pragma unroll
    for (int mt = 0; mt < 2; ++mt)
        #pragma unroll
        for (int kh = 0; kh < 2; ++kh) {
            int row = wv * 32 + mt * 16 + col;
            int p0 = kh * 8 + g * 2;
            v4f xa = *(const v4f*)&sX[p0 * PS + row * 4];
            v4f xb = *(const v4f*)&sX[(p0 + 1) * PS + row * 4];
            uint4v fr;
            fr[0] = bf16rne(xa[0]) | (bf16rne(xa[1]) << 16);
            fr[1] = bf16rne(xa[2]) | (bf16rne(xa[3]) << 16);
            fr[2] = bf16rne(xb[0]) | (bf16rne(xb[1]) << 16);
            fr[3] = bf16rne(xb[2]) | (bf16rne(xb[3]) << 16);
            Ah[mt][kh] = __builtin_bit_cast(bf16x8, fr);
        }

    // per-lane top-2 per (mt, r) slot
    float tb1[2][4], tb2[2][4];
    int ti1[2][4], ti2[2][4];
    #pragma unroll
    for (int mt = 0; mt < 2; ++mt)
        #pragma unroll
        for (int r = 0; r < 4; ++r) {
            tb1[mt][r] = -3.0e38f; tb2[mt][r] = -3.0e38f;
            ti1[mt][r] = 0; ti2[mt][r] = 0;
        }

    for (int jt = 0; jt < 4; ++jt) {
        const uint* eh = ehg + jt * TB;
        #pragma unroll
        for (int nt = 0; nt < 8; ++nt) {
            int i0 = (0 * 4 + g) * PS + (nt * 16 + col) * 4;
            int i1x = (1 * 4 + g) * PS + (nt * 16 + col) * 4;
            bf16x8 Bh0 = ldfragg(eh, i0);
            bf16x8 Bh1 = ldfragg(eh, i1x);
            float e2 = -0.5f * sEE[jt * 128 + nt * 16 + col];
            f32x4 acc0 = {e2, e2, e2, e2};
            f32x4 acc1 = acc0;
            acc0 = __builtin_amdgcn_mfma_f32_16x16x32_bf16(Ah[0][0], Bh0, acc0, 0, 0, 0);
            acc1 = __builtin_amdgcn_mfma_f32_16x16x32_bf16(Ah[1][0], Bh0, acc1, 0, 0, 0);
            acc0 = __builtin_amdgcn_mfma_f32_16x16x32_bf16(Ah[0][1], Bh1, acc0, 0, 0, 0);
            acc1 = __builtin_amdgcn_mfma_f32_16x16x32_bf16(Ah[1][1], Bh1, acc1, 0, 0, 0);
            int jc = jt * 128 + nt * 16 + col;
            #pragma unroll
            for (int r = 0; r < 4; ++r) {
                float s0 = acc0[r];
                bool g1 = s0 > tb1[0][r];
                bool g2 = s0 > tb2[0][r];
                ti2[0][r] = g1 ? ti1[0][r] : (g2 ? jc : ti2[0][r]);
                tb2[0][r] = __builtin_amdgcn_fmed3f(s0, tb1[0][r], tb2[0][r]);
                ti1[0][r] = g1 ? jc : ti1[0][r];
                tb1[0][r] = fmaxf(s0, tb1[0][r]);
                float s1 = acc1[r];
                bool h1b = s1 > tb1[1][r];
                bool h2b = s1 > tb2[1][r];
                ti2[1][r] = h1b ? ti1[1][r] : (h2b ? jc : ti2[1][r]);
                tb2[1][r] = __builtin_amdgcn_fmed3f(s1, tb1[1][r], tb2[1][r]);
                ti1[1][r] = h1b ? jc : ti1[1][r];
                tb1[1][r] = fmaxf(s1, tb1[1][r]);
            }
        }
    }

    // 16-lane top-2 merge per point; lane col==0 publishes candidates
    #pragma unroll
    for (int mt = 0; mt < 2; ++mt)
        #pragma unroll
        for (int r = 0; r < 4; ++r) {
            float a1 = tb1[mt][r], a2 = tb2[mt][r];
            int j1 = ti1[mt][r], j2 = ti2[mt][r];
            #pragma unroll
            for (int off = 8; off > 0; off >>= 1) {
                float c1 = __shfl_xor(a1, off, 16); int k1 = __shfl_xor(j1, off, 16);
                float c2v = __shfl_xor(a2, off, 16); int k2 = __shfl_xor(j2, off, 16);
                bool af = (a1 > c1) || (a1 == c1 && j1 < k1);
                float n1 = af ? a1 : c1; int nj1 = af ? j1 : k1;
                float lx = af ? c1 : a1; int lj = af ? k1 : j1;   // loser of tops
                float wx = af ? a2 : c2v; int wj = af ? j2 : k2;  // winner's 2nd
                bool wf = (wx > lx) || (wx == lx && wj < lj);
                a1 = n1; j1 = nj1;
                a2 = wf ? wx : lx; j2 = wf ? wj : lj;
            }
            if (col == 0) {
                int p = wv * 32 + mt * 16 + g * 4 + r;
                sCand[p * 2] = j1;
                sCand[p * 2 + 1] = j2;
            }
        }
    __syncthreads();

    // ---- exact fp32 rescore of both candidates (2 threads per point) ----
    int p = t & 127, wc = t >> 7;
    int c = sCand[p * 2 + wc];
    const v4f* erow = (const v4f*)(embed + c * 64);
    float dot = 0.f;
    #pragma unroll
    for (int plane = 0; plane < 16; ++plane) {
        v4f xq = *(const v4f*)&sX[plane * PS + p * 4];
        v4f e4 = erow[plane];
        dot = fmaf(xq[0], e4[0], dot);
        dot = fmaf(xq[1], e4[1], dot);
        dot = fmaf(xq[2], e4[2], dot);
        dot = fmaf(xq[3], e4[3], dot);
    }
    float sx = fmaf(2.f, dot, -sEE[c]);
    sRes[t] = sx;
    __syncthreads();
    float so = sRes[t ^ 128];
    int co = sCand[p * 2 + (1 - wc)];
    bool win = (sx > so) || (sx == so && c < co);

    // winner: ids + quantized + commit contribution
    float cl = 0.f;
    if (win) {
        int h = (h2 << 1) + (p >> 6), w = p & 63;
        ws_ids[b * HW + h2 * 128 + p] = c;                 // natural order
        out_ids[b * HW + w * 64 + h] = (float)c;           // (b,w,h) quirk
        float* qg = out_q + (size_t)b * (EMB * HW) + h2 * 128 + p;
        #pragma unroll
        for (int plane = 0; plane < 16; ++plane) {
            v4f xq = *(const v4f*)&sX[plane * PS + p * 4];
            v4f e4 = erow[plane];
            #pragma unroll
            for (int v = 0; v < 4; ++v) {
                int ch = plane * 4 + v;
                qg[(size_t)ch * HW] = e4[v];
                float d = xq[v] - e4[v];
                cl = fmaf(d, d, cl);
            }
        }
    }
    #pragma unroll
    for (int off = 32; off > 0; off >>= 1) cl += __shfl_down(cl, off);
    if ((t & 63) == 0) cred[t >> 6] = cl;
    __syncthreads();
    if (t == 0)
        unsafeAtomicAdd(&ws[WS_COMMIT], (cred[0] + cred[1]) + (cred[2] + cred[3]));
}

// ------------------------------------------------- stats: esum + counts
// 2048 blocks = (b, ch). Tiny LDS table -> high occupancy; ids in registers.
__global__ __launch_bounds__(256) void vq_stats(
    const float* __restrict__ input, const int* __restrict__ ws_ids,
    float* __restrict__ ws) {
    __shared__ float es[520];
    __shared__ float cnt_s[DICT];

    int t = threadIdx.x;
    int bc = blockIdx.x;
    int b = bc >> 6, ch = bc & 63;

    #pragma unroll
    for (int i = t; i < 520; i += 256) es[i] = 0.f;
    if (ch == 0)
        for (int i = t; i < DICT; i += 256) cnt_s[i] = 0.f;

    const int* idg = ws_ids + b * HW;
    int4 idv[4];
    #pragma unroll
    for (int it = 0; it < 4; ++it)
        idv[it] = *(const int4*)(idg + (t + it * 256) * 4);
    __syncthreads();

    const float* xg = input + (size_t)b * (EMB * HW) + (size_t)ch * HW;
    #pragma unroll
    for (int it = 0; it < 4; ++it) {
        v4f x = *(const v4f*)(xg + (t + it * 256) * 4);
        atomicAdd(&es[idv[it].x], x.x);
        atomicAdd(&es[idv[it].y], x.y);
        atomicAdd(&es[idv[it].z], x.z);
        atomicAdd(&es[idv[it].w], x.w);
    }
    if (ch == 0) {
        #pragma unroll
        for (int it = 0; it < 4; ++it) {
            atomicAdd(&cnt_s[idv[it].x], 1.f);
            atomicAdd(&cnt_s[idv[it].y], 1.f);
            atomicAdd(&cnt_s[idv[it].z], 1.f);
            atomicAdd(&cnt_s[idv[it].w], 1.f);
        }
    }
    __syncthreads();

    #pragma unroll
    for (int i = t; i < DICT; i += 256) {
        float v = es[i];
        if (v != 0.f)
            unsafeAtomicAdd(&ws[WS_ESUM + ch * DICT + i], v);
    }
    if (ch == 0)
        for (int i = t; i < DICT; i += 256) {
            float c = cnt_s[i];
            if (c != 0.f) unsafeAtomicAdd(&ws[WS_COUNTS + i], c);
        }
}

// ---------------------------------------------------- finalize (fused fin1+fin2)
// 128 blocks x 256; each block redundantly reduces n (deterministic).
__global__ __launch_bounds__(256) void vq_fin(
    const float* __restrict__ embed_avg, const float* __restrict__ cluster_size,
    const float* __restrict__ ws, float* __restrict__ out_embed,
    float* __restrict__ out_cs, float* __restrict__ out_avg,
    float* __restrict__ out_loss) {
    __shared__ float red[256];
    int t = threadIdx.x, blk = blockIdx.x;

    float ncs0 = cluster_size[t] * MOM + ws[WS_COUNTS + t] * OMOM;
    float ncs1 = cluster_size[t + 256] * MOM + ws[WS_COUNTS + t + 256] * OMOM;
    if (blk == 0) {
        out_cs[t] = ncs0;
        out_cs[t + 256] = ncs1;
        if (t == 0)
            out_loss[0] = ws[WS_COMMIT] * (1.0f / (float)((size_t)NPTS * EMB));
    }
    red[t] = ncs0 + ncs1;
    __syncthreads();
    #pragma unroll
    for (int off = 128; off > 0; off >>= 1) {
        if (t < off) red[t] += red[t + off];
        __syncthreads();
    }
    float n = red[0];

    int idx = blk * 256 + t;          // idx = ch*512 + d
    int ch = idx >> 9, d = idx & 511;
    float avg = embed_avg[idx] * MOM + ws[WS_ESUM + idx] * OMOM;
    out_avg[idx] = avg;
    float ncs = cluster_size[d] * MOM + ws[WS_COUNTS + d] * OMOM;
    float cs = n * (ncs + EPSV) / (n + (float)DICT * EPSV);
    out_embed[d * EMB + ch] = avg / cs;
}

extern "C" void kernel_launch(void* const* d_in, const int* in_sizes, int n_in,
                              void* d_out, int out_size, void* d_ws, size_t ws_size,
                              hipStream_t stream) {
    const float* input        = (const float*)d_in[0];
    const float* embed        = (const float*)d_in[1];
    const float* cluster_size = (const float*)d_in[2];
    const float* embed_avg    = (const float*)d_in[3];

    float* out   = (float*)d_out;
    float* q     = out;                         // 8388608
    float* loss  = out + 8388608;               // 1
    float* ids   = out + 8388609;               // 131072
    float* oemb  = out + 8519681;               // 32768
    float* ocs   = out + 8552449;               // 512
    float* oavg  = out + 8552961;               // 32768
    float* ws    = (float*)d_ws;

    vq_prep  <<<32, 256, 0, stream>>>(embed, ws, (uint*)(ws + WS_EHG), ws + WS_EE);
    vq_argmax<<<1024, 256, 0, stream>>>(input, (const uint*)(ws + WS_EHG),
                                        ws + WS_EE, embed, q, ids,
                                        (int*)(ws + WS_IDS), ws);
    vq_stats <<<2048, 256, 0, stream>>>(input, (const int*)(ws + WS_IDS), ws);
    vq_fin   <<<128, 256, 0, stream>>>(embed_avg, cluster_size, ws, oemb, ocs,
                                       oavg, loss);
}

// Round 12
// 76.799 us; speedup vs baseline: 1.9681x; 1.9681x over previous
//
#include <hip/hip_runtime.h>

#define EMB 64
#define DICT 512
#define HW 4096              // 64*64
#define NPTS (32 * HW)       // 131072
#define MOM 0.99f
#define OMOM 0.01f
#define EPSV 1e-5f

typedef float v4f __attribute__((ext_vector_type(4)));
typedef unsigned int uint;
typedef uint uint4v __attribute__((ext_vector_type(4)));
typedef short short8 __attribute__((ext_vector_type(8)));
typedef __bf16 bf16x8 __attribute__((ext_vector_type(8)));
typedef float f32x4 __attribute__((ext_vector_type(4)));

// ws layout (dword offsets)
#define WS_COMMIT 0
#define WS_COUNTS 64                      // 512
#define WS_ESUM   1024                    // 64*512
#define WS_ZERO_FLOATS 33792              // zeroed by vq_prep each call
#define WS_EE     33792                   // 512 (fp32 ||e||^2)
#define WS_EHG    34320                   // 4 tiles * 4160 (packed bf16-hi E)
#define WS_IDS    67600                   // 131072 ints (natural pixel order)

#define PS 520      // plane stride in dwords: 130 rows x 4 dwords
#define TB 4160     // E tile blob: 8 planes (kh*4+g)

#define ESCALE 65536.0f
#define EINV   (1.0f / 65536.0f)

__device__ __forceinline__ uint bf16rne(float x) {
    uint u = __float_as_uint(x);
    return (u + 0x7fffu + ((u >> 16) & 1u)) >> 16;
}

__device__ __forceinline__ bf16x8 ldfragg(const uint* s, int idx) {
    return __builtin_bit_cast(bf16x8, *(const short8*)(s + idx));
}

// ------------------------------------------------- prep: zero ws + pack E-hi + ||e||^2
// 32 blocks x 256; block = 16 codes. Also grid-stride zeroes accumulators.
__global__ __launch_bounds__(256) void vq_prep(const float* __restrict__ embed,
                                               float* __restrict__ ws,
                                               uint* __restrict__ ehg,
                                               float* __restrict__ ee) {
    int t = threadIdx.x;
    int blk = blockIdx.x;
    for (int i = blk * 256 + t; i < WS_ZERO_FLOATS; i += 32 * 256) ws[i] = 0.f;

    int jl = t >> 4;           // 0..15
    int ci = t & 15;
    int j  = blk * 16 + jl;
    float nrm = 0.f;
    #pragma unroll
    for (int it = 0; it < 2; ++it) {
        int c2 = ci + it * 16;
        float x0 = embed[j * 64 + 2 * c2];
        float x1 = embed[j * 64 + 2 * c2 + 1];
        nrm = fmaf(x0, x0, nrm);
        nrm = fmaf(x1, x1, nrm);
        uint h0 = bf16rne(x0), h1 = bf16rne(x1);
        int plane = (c2 >> 4) * 4 + ((c2 >> 2) & 3);
        int idx = (j >> 7) * TB + plane * PS + (j & 127) * 4 + (c2 & 3);
        ehg[idx] = h0 | (h1 << 16);
    }
    #pragma unroll
    for (int off = 8; off > 0; off >>= 1) nrm += __shfl_xor(nrm, off, 16);
    if (ci == 0) ee[j] = nrm;
}

// ------------------------------------------------- MFMA argmax + exact rescore
// block: 128 points, 4 waves. Hi-only bf16 MFMA (error ~0.05) + per-lane top-2
// + 16-lane merge + exact fp32 rescore of 2 candidates. X in LDS as fp32.
__global__ __launch_bounds__(256, 4) void vq_argmax(
    const float* __restrict__ input, const uint* __restrict__ ehg,
    const float* __restrict__ ee, const float* __restrict__ embed,
    float* __restrict__ out_q, float* __restrict__ out_ids,
    int* __restrict__ ws_ids, float* __restrict__ ws) {
    __shared__ float sX[16 * PS];      // fp32: [plane=ch>>2][point][ch&3]
    __shared__ float sEE[512];
    __shared__ int sCand[256];
    __shared__ float sRes[256];
    __shared__ float cred[4];

    int t = threadIdx.x;
    int blk = blockIdx.x;
    int b = blk >> 5, h2 = blk & 31;

    // ---- stage X (fp32, no conversion) ----
    {
        int p = t & 127;
        const float* xg = input + (size_t)b * (EMB * HW) + h2 * 128 + p;
        int ch0 = (t >> 7) * 32;
        #pragma unroll
        for (int i = 0; i < 32; ++i) {
            int ch = ch0 + i;
            sX[(ch >> 2) * PS + p * 4 + (ch & 3)] = xg[(size_t)ch * HW];
        }
        sEE[t] = ee[t];
        sEE[t + 256] = ee[t + 256];
    }
    __syncthreads();

    int l = t & 63, wv = t >> 6;
    int g = l >> 4, col = l & 15;

    // A fragments (bf16-hi of X), built once. Fragment (mt,kh): channels
    // [kh*32+g*8, +8) of row wv*32+mt*16+col; dword v = pack(ch0+2v, ch0+2v+1).
    bf16x8 Ah[2][2];
    #pragma unroll
    for (int mt = 0; mt < 2; ++mt)
        #pragma unroll
        for (int kh = 0; kh < 2; ++kh) {
            int row = wv * 32 + mt * 16 + col;
            int p0 = kh * 8 + g * 2;
            v4f xa = *(const v4f*)&sX[p0 * PS + row * 4];
            v4f xb = *(const v4f*)&sX[(p0 + 1) * PS + row * 4];
            uint4v fr;
            fr[0] = bf16rne(xa[0]) | (bf16rne(xa[1]) << 16);
            fr[1] = bf16rne(xa[2]) | (bf16rne(xa[3]) << 16);
            fr[2] = bf16rne(xb[0]) | (bf16rne(xb[1]) << 16);
            fr[3] = bf16rne(xb[2]) | (bf16rne(xb[3]) << 16);
            Ah[mt][kh] = __builtin_bit_cast(bf16x8, fr);
        }

    // per-lane top-2 per (mt, r) slot
    float tb1[2][4], tb2[2][4];
    int ti1[2][4], ti2[2][4];
    #pragma unroll
    for (int mt = 0; mt < 2; ++mt)
        #pragma unroll
        for (int r = 0; r < 4; ++r) {
            tb1[mt][r] = -3.0e38f; tb2[mt][r] = -3.0e38f;
            ti1[mt][r] = 0; ti2[mt][r] = 0;
        }

    for (int jt = 0; jt < 4; ++jt) {
        const uint* eh = ehg + jt * TB;
        #pragma unroll
        for (int nt = 0; nt < 8; ++nt) {
            int i0 = (0 * 4 + g) * PS + (nt * 16 + col) * 4;
            int i1x = (1 * 4 + g) * PS + (nt * 16 + col) * 4;
            bf16x8 Bh0 = ldfragg(eh, i0);
            bf16x8 Bh1 = ldfragg(eh, i1x);
            float e2 = -0.5f * sEE[jt * 128 + nt * 16 + col];
            f32x4 acc0 = {e2, e2, e2, e2};
            f32x4 acc1 = acc0;
            acc0 = __builtin_amdgcn_mfma_f32_16x16x32_bf16(Ah[0][0], Bh0, acc0, 0, 0, 0);
            acc1 = __builtin_amdgcn_mfma_f32_16x16x32_bf16(Ah[1][0], Bh0, acc1, 0, 0, 0);
            acc0 = __builtin_amdgcn_mfma_f32_16x16x32_bf16(Ah[0][1], Bh1, acc0, 0, 0, 0);
            acc1 = __builtin_amdgcn_mfma_f32_16x16x32_bf16(Ah[1][1], Bh1, acc1, 0, 0, 0);
            int jc = jt * 128 + nt * 16 + col;
            #pragma unroll
            for (int r = 0; r < 4; ++r) {
                float s0 = acc0[r];
                bool g1 = s0 > tb1[0][r];
                bool g2 = s0 > tb2[0][r];
                ti2[0][r] = g1 ? ti1[0][r] : (g2 ? jc : ti2[0][r]);
                tb2[0][r] = __builtin_amdgcn_fmed3f(s0, tb1[0][r], tb2[0][r]);
                ti1[0][r] = g1 ? jc : ti1[0][r];
                tb1[0][r] = fmaxf(s0, tb1[0][r]);
                float s1 = acc1[r];
                bool h1b = s1 > tb1[1][r];
                bool h2b = s1 > tb2[1][r];
                ti2[1][r] = h1b ? ti1[1][r] : (h2b ? jc : ti2[1][r]);
                tb2[1][r] = __builtin_amdgcn_fmed3f(s1, tb1[1][r], tb2[1][r]);
                ti1[1][r] = h1b ? jc : ti1[1][r];
                tb1[1][r] = fmaxf(s1, tb1[1][r]);
            }
        }
    }

    // 16-lane top-2 merge per point; lane col==0 publishes candidates
    #pragma unroll
    for (int mt = 0; mt < 2; ++mt)
        #pragma unroll
        for (int r = 0; r < 4; ++r) {
            float a1 = tb1[mt][r], a2 = tb2[mt][r];
            int j1 = ti1[mt][r], j2 = ti2[mt][r];
            #pragma unroll
            for (int off = 8; off > 0; off >>= 1) {
                float c1 = __shfl_xor(a1, off, 16); int k1 = __shfl_xor(j1, off, 16);
                float c2v = __shfl_xor(a2, off, 16); int k2 = __shfl_xor(j2, off, 16);
                bool af = (a1 > c1) || (a1 == c1 && j1 < k1);
                float n1 = af ? a1 : c1; int nj1 = af ? j1 : k1;
                float lx = af ? c1 : a1; int lj = af ? k1 : j1;   // loser of tops
                float wx = af ? a2 : c2v; int wj = af ? j2 : k2;  // winner's 2nd
                bool wf = (wx > lx) || (wx == lx && wj < lj);
                a1 = n1; j1 = nj1;
                a2 = wf ? wx : lx; j2 = wf ? wj : lj;
            }
            if (col == 0) {
                int p = wv * 32 + mt * 16 + g * 4 + r;
                sCand[p * 2] = j1;
                sCand[p * 2 + 1] = j2;
            }
        }
    __syncthreads();

    // ---- exact fp32 rescore of both candidates (2 threads per point) ----
    int p = t & 127, wc = t >> 7;
    int c = sCand[p * 2 + wc];
    const v4f* erow = (const v4f*)(embed + c * 64);
    float dot = 0.f;
    #pragma unroll
    for (int plane = 0; plane < 16; ++plane) {
        v4f xq = *(const v4f*)&sX[plane * PS + p * 4];
        v4f e4 = erow[plane];
        dot = fmaf(xq[0], e4[0], dot);
        dot = fmaf(xq[1], e4[1], dot);
        dot = fmaf(xq[2], e4[2], dot);
        dot = fmaf(xq[3], e4[3], dot);
    }
    float sx = fmaf(2.f, dot, -sEE[c]);
    sRes[t] = sx;
    __syncthreads();
    float so = sRes[t ^ 128];
    int co = sCand[p * 2 + (1 - wc)];
    bool win = (sx > so) || (sx == so && c < co);

    // winner: ids + quantized + commit contribution
    float cl = 0.f;
    if (win) {
        int h = (h2 << 1) + (p >> 6), w = p & 63;
        ws_ids[b * HW + h2 * 128 + p] = c;                 // natural order
        out_ids[b * HW + w * 64 + h] = (float)c;           // (b,w,h) quirk
        float* qg = out_q + (size_t)b * (EMB * HW) + h2 * 128 + p;
        #pragma unroll
        for (int plane = 0; plane < 16; ++plane) {
            v4f xq = *(const v4f*)&sX[plane * PS + p * 4];
            v4f e4 = erow[plane];
            #pragma unroll
            for (int v = 0; v < 4; ++v) {
                int ch = plane * 4 + v;
                qg[(size_t)ch * HW] = e4[v];
                float d = xq[v] - e4[v];
                cl = fmaf(d, d, cl);
            }
        }
    }
    #pragma unroll
    for (int off = 32; off > 0; off >>= 1) cl += __shfl_down(cl, off);
    if ((t & 63) == 0) cred[t >> 6] = cl;
    __syncthreads();
    if (t == 0)
        unsafeAtomicAdd(&ws[WS_COMMIT], (cred[0] + cred[1]) + (cred[2] + cred[3]));
}

// ------------------------------------------------- stats: esum + counts
// 1024 blocks = (b, 32 groups of 2 channels). LDS histogram in FIXED-POINT
// uint via native non-returning ds_add_u32 (float LDS atomics stall: R11).
__global__ __launch_bounds__(256) void vq_stats(
    const float* __restrict__ input, const int* __restrict__ ws_ids,
    float* __restrict__ ws) {
    __shared__ uint es[2 * 520];
    __shared__ uint cnt_s[DICT];

    int t = threadIdx.x;
    int bc = blockIdx.x;
    int b = bc >> 5, cg = bc & 31;

    #pragma unroll
    for (int i = t; i < 2 * 520; i += 256) es[i] = 0u;
    if (cg == 0)
        for (int i = t; i < DICT; i += 256) cnt_s[i] = 0u;

    const int* idg = ws_ids + b * HW;
    int4 idv[4];
    #pragma unroll
    for (int it = 0; it < 4; ++it)
        idv[it] = *(const int4*)(idg + (t + it * 256) * 4);
    __syncthreads();

    #pragma unroll
    for (int chl = 0; chl < 2; ++chl) {
        const float* xg = input + (size_t)b * (EMB * HW) + (size_t)(cg * 2 + chl) * HW;
        uint* esr = es + chl * 520;
        #pragma unroll
        for (int it = 0; it < 4; ++it) {
            v4f x = *(const v4f*)(xg + (t + it * 256) * 4);
            atomicAdd(&esr[idv[it].x], (uint)__float2int_rn(x.x * ESCALE));
            atomicAdd(&esr[idv[it].y], (uint)__float2int_rn(x.y * ESCALE));
            atomicAdd(&esr[idv[it].z], (uint)__float2int_rn(x.z * ESCALE));
            atomicAdd(&esr[idv[it].w], (uint)__float2int_rn(x.w * ESCALE));
        }
    }
    if (cg == 0) {
        #pragma unroll
        for (int it = 0; it < 4; ++it) {
            atomicAdd(&cnt_s[idv[it].x], 1u);
            atomicAdd(&cnt_s[idv[it].y], 1u);
            atomicAdd(&cnt_s[idv[it].z], 1u);
            atomicAdd(&cnt_s[idv[it].w], 1u);
        }
    }
    __syncthreads();

    #pragma unroll
    for (int i = t; i < 2 * DICT; i += 256) {
        int chl = i >> 9, j = i & 511;
        int v = (int)es[chl * 520 + j];
        if (v != 0)
            unsafeAtomicAdd(&ws[WS_ESUM + (cg * 2 + chl) * DICT + j],
                            (float)v * EINV);
    }
    if (cg == 0)
        for (int i = t; i < DICT; i += 256) {
            uint c = cnt_s[i];
            if (c != 0u) unsafeAtomicAdd(&ws[WS_COUNTS + i], (float)c);
        }
}

// ---------------------------------------------------- finalize (fused fin1+fin2)
// 128 blocks x 256; each block redundantly reduces n (deterministic).
__global__ __launch_bounds__(256) void vq_fin(
    const float* __restrict__ embed_avg, const float* __restrict__ cluster_size,
    const float* __restrict__ ws, float* __restrict__ out_embed,
    float* __restrict__ out_cs, float* __restrict__ out_avg,
    float* __restrict__ out_loss) {
    __shared__ float red[256];
    int t = threadIdx.x, blk = blockIdx.x;

    float ncs0 = cluster_size[t] * MOM + ws[WS_COUNTS + t] * OMOM;
    float ncs1 = cluster_size[t + 256] * MOM + ws[WS_COUNTS + t + 256] * OMOM;
    if (blk == 0) {
        out_cs[t] = ncs0;
        out_cs[t + 256] = ncs1;
        if (t == 0)
            out_loss[0] = ws[WS_COMMIT] * (1.0f / (float)((size_t)NPTS * EMB));
    }
    red[t] = ncs0 + ncs1;
    __syncthreads();
    #pragma unroll
    for (int off = 128; off > 0; off >>= 1) {
        if (t < off) red[t] += red[t + off];
        __syncthreads();
    }
    float n = red[0];

    int idx = blk * 256 + t;          // idx = ch*512 + d
    int ch = idx >> 9, d = idx & 511;
    float avg = embed_avg[idx] * MOM + ws[WS_ESUM + idx] * OMOM;
    out_avg[idx] = avg;
    float ncs = cluster_size[d] * MOM + ws[WS_COUNTS + d] * OMOM;
    float cs = n * (ncs + EPSV) / (n + (float)DICT * EPSV);
    out_embed[d * EMB + ch] = avg / cs;
}

extern "C" void kernel_launch(void* const* d_in, const int* in_sizes, int n_in,
                              void* d_out, int out_size, void* d_ws, size_t ws_size,
                              hipStream_t stream) {
    const float* input        = (const float*)d_in[0];
    const float* embed        = (const float*)d_in[1];
    const float* cluster_size = (const float*)d_in[2];
    const float* embed_avg    = (const float*)d_in[3];

    float* out   = (float*)d_out;
    float* q     = out;                         // 8388608
    float* loss  = out + 8388608;               // 1
    float* ids   = out + 8388609;               // 131072
    float* oemb  = out + 8519681;               // 32768
    float* ocs   = out + 8552449;               // 512
    float* oavg  = out + 8552961;               // 32768
    float* ws    = (float*)d_ws;

    vq_prep  <<<32, 256, 0, stream>>>(embed, ws, (uint*)(ws + WS_EHG), ws + WS_EE);
    vq_argmax<<<1024, 256, 0, stream>>>(input, (const uint*)(ws + WS_EHG),
                                        ws + WS_EE, embed, q, ids,
                                        (int*)(ws + WS_IDS), ws);
    vq_stats <<<1024, 256, 0, stream>>>(input, (const int*)(ws + WS_IDS), ws);
    vq_fin   <<<128, 256, 0, stream>>>(embed_avg, cluster_size, ws, oemb, ocs,
                                       oavg, loss);
}

// Round 13
// 66.494 us; speedup vs baseline: 2.2732x; 1.1550x over previous
//
#include <hip/hip_runtime.h>

#define EMB 64
#define DICT 512
#define HW 4096              // 64*64
#define NPTS (32 * HW)       // 131072
#define MOM 0.99f
#define OMOM 0.01f
#define EPSV 1e-5f

typedef float v4f __attribute__((ext_vector_type(4)));
typedef unsigned int uint;
typedef uint uint4v __attribute__((ext_vector_type(4)));
typedef short short8 __attribute__((ext_vector_type(8)));
typedef __bf16 bf16x8 __attribute__((ext_vector_type(8)));
typedef float f32x4 __attribute__((ext_vector_type(4)));

// ws layout (dword offsets)
#define WS_COMMIT 0
#define WS_COUNTS 64                      // 512
#define WS_ESUM   1024                    // 64*512
#define WS_ZERO_FLOATS 33792              // zeroed by vq_prep each call
#define WS_EE     33792                   // 512 (fp32 ||e||^2)
#define WS_EHG    34320                   // 4 tiles * 4160 (packed bf16-hi E)
#define WS_IDS    67600                   // 131072 ints (natural pixel order)

#define PS 520      // plane stride in dwords: 130 rows x 4 dwords
#define TB 4160     // E tile blob: 8 planes (kh*4+g)

#define ESCALE 65536.0f
#define EINV   (1.0f / 65536.0f)

__device__ __forceinline__ uint bf16rne(float x) {
    uint u = __float_as_uint(x);
    return (u + 0x7fffu + ((u >> 16) & 1u)) >> 16;
}

__device__ __forceinline__ bf16x8 ldfragg(const uint* s, int idx) {
    return __builtin_bit_cast(bf16x8, *(const short8*)(s + idx));
}

// ------------------------------------------------- prep: zero ws + pack E-hi + ||e||^2
// 32 blocks x 256; block = 16 codes. Also grid-stride zeroes accumulators.
__global__ __launch_bounds__(256) void vq_prep(const float* __restrict__ embed,
                                               float* __restrict__ ws,
                                               uint* __restrict__ ehg,
                                               float* __restrict__ ee) {
    int t = threadIdx.x;
    int blk = blockIdx.x;
    for (int i = blk * 256 + t; i < WS_ZERO_FLOATS; i += 32 * 256) ws[i] = 0.f;

    int jl = t >> 4;           // 0..15
    int ci = t & 15;
    int j  = blk * 16 + jl;
    float nrm = 0.f;
    #pragma unroll
    for (int it = 0; it < 2; ++it) {
        int c2 = ci + it * 16;
        float x0 = embed[j * 64 + 2 * c2];
        float x1 = embed[j * 64 + 2 * c2 + 1];
        nrm = fmaf(x0, x0, nrm);
        nrm = fmaf(x1, x1, nrm);
        uint h0 = bf16rne(x0), h1 = bf16rne(x1);
        int plane = (c2 >> 4) * 4 + ((c2 >> 2) & 3);
        int idx = (j >> 7) * TB + plane * PS + (j & 127) * 4 + (c2 & 3);
        ehg[idx] = h0 | (h1 << 16);
    }
    #pragma unroll
    for (int off = 8; off > 0; off >>= 1) nrm += __shfl_xor(nrm, off, 16);
    if (ci == 0) ee[j] = nrm;
}

// ------------------------------------------------- MFMA argmax + exact rescore
// block: 128 points, 4 waves. Hi-only bf16 MFMA + PACKED top-2 (index in low
// 9 mantissa bits -> 4 VALU/update, no index regs) + exact fp32 rescore.
__global__ __launch_bounds__(256, 4) void vq_argmax(
    const float* __restrict__ input, const uint* __restrict__ ehg,
    const float* __restrict__ ee, const float* __restrict__ embed,
    float* __restrict__ out_q, float* __restrict__ out_ids,
    int* __restrict__ ws_ids, float* __restrict__ ws) {
    __shared__ float sX[16 * PS];      // fp32: [plane=ch>>2][point][ch&3]
    __shared__ float sEE[512];
    __shared__ int sCand[256];
    __shared__ float sRes[256];
    __shared__ float cred[4];

    int t = threadIdx.x;
    int blk = blockIdx.x;
    int b = blk >> 5, h2 = blk & 31;

    // ---- stage X (fp32, no conversion) ----
    {
        int p = t & 127;
        const float* xg = input + (size_t)b * (EMB * HW) + h2 * 128 + p;
        int ch0 = (t >> 7) * 32;
        #pragma unroll
        for (int i = 0; i < 32; ++i) {
            int ch = ch0 + i;
            sX[(ch >> 2) * PS + p * 4 + (ch & 3)] = xg[(size_t)ch * HW];
        }
        sEE[t] = ee[t];
        sEE[t + 256] = ee[t + 256];
    }
    __syncthreads();

    int l = t & 63, wv = t >> 6;
    int g = l >> 4, col = l & 15;

    // A fragments (bf16-hi of X), built once.
    bf16x8 Ah[2][2];
    #pragma unroll
    for (int mt = 0; mt < 2; ++mt)
        #pragma unroll
        for (int kh = 0; kh < 2; ++kh) {
            int row = wv * 32 + mt * 16 + col;
            int p0 = kh * 8 + g * 2;
            v4f xa = *(const v4f*)&sX[p0 * PS + row * 4];
            v4f xb = *(const v4f*)&sX[(p0 + 1) * PS + row * 4];
            uint4v fr;
            fr[0] = bf16rne(xa[0]) | (bf16rne(xa[1]) << 16);
            fr[1] = bf16rne(xa[2]) | (bf16rne(xa[3]) << 16);
            fr[2] = bf16rne(xb[0]) | (bf16rne(xb[1]) << 16);
            fr[3] = bf16rne(xb[2]) | (bf16rne(xb[3]) << 16);
            Ah[mt][kh] = __builtin_bit_cast(bf16x8, fr);
        }

    // per-lane PACKED top-2 per (mt, r) slot: score bits with low 9 mantissa
    // bits replaced by (511 - code). Ordering == score ordering (2^-14 perturb,
    // backstopped by exact rescore); ties prefer smaller code (positive scores).
    float tb1[2][4], tb2[2][4];
    #pragma unroll
    for (int mt = 0; mt < 2; ++mt)
        #pragma unroll
        for (int r = 0; r < 4; ++r) { tb1[mt][r] = -3.0e38f; tb2[mt][r] = -3.0e38f; }

    for (int jt = 0; jt < 4; ++jt) {
        const uint* eh = ehg + jt * TB;
        #pragma unroll
        for (int nt = 0; nt < 8; ++nt) {
            int i0 = (0 * 4 + g) * PS + (nt * 16 + col) * 4;
            int i1x = (1 * 4 + g) * PS + (nt * 16 + col) * 4;
            bf16x8 Bh0 = ldfragg(eh, i0);
            bf16x8 Bh1 = ldfragg(eh, i1x);
            float e2 = -0.5f * sEE[jt * 128 + nt * 16 + col];
            f32x4 acc0 = {e2, e2, e2, e2};
            f32x4 acc1 = acc0;
            acc0 = __builtin_amdgcn_mfma_f32_16x16x32_bf16(Ah[0][0], Bh0, acc0, 0, 0, 0);
            acc1 = __builtin_amdgcn_mfma_f32_16x16x32_bf16(Ah[1][0], Bh0, acc1, 0, 0, 0);
            acc0 = __builtin_amdgcn_mfma_f32_16x16x32_bf16(Ah[0][1], Bh1, acc0, 0, 0, 0);
            acc1 = __builtin_amdgcn_mfma_f32_16x16x32_bf16(Ah[1][1], Bh1, acc1, 0, 0, 0);
            uint tag = (uint)(511 - (jt * 128 + nt * 16 + col));
            #pragma unroll
            for (int r = 0; r < 4; ++r) {
                float sp0 = __uint_as_float(
                    (__float_as_uint(acc0[r]) & 0xFFFFFE00u) | tag);
                float o1 = tb1[0][r];
                tb1[0][r] = fmaxf(sp0, o1);
                tb2[0][r] = __builtin_amdgcn_fmed3f(sp0, o1, tb2[0][r]);
                float sp1 = __uint_as_float(
                    (__float_as_uint(acc1[r]) & 0xFFFFFE00u) | tag);
                float p1 = tb1[1][r];
                tb1[1][r] = fmaxf(sp1, p1);
                tb2[1][r] = __builtin_amdgcn_fmed3f(sp1, p1, tb2[1][r]);
            }
        }
    }

    // 16-lane top-2 merge per point (packed values); col==0 publishes codes
    #pragma unroll
    for (int mt = 0; mt < 2; ++mt)
        #pragma unroll
        for (int r = 0; r < 4; ++r) {
            float t1 = tb1[mt][r], t2 = tb2[mt][r];
            #pragma unroll
            for (int off = 8; off > 0; off >>= 1) {
                float o1 = __shfl_xor(t1, off, 16);
                float o2 = __shfl_xor(t2, off, 16);
                float hi = fmaxf(t1, o1);
                float lo = fminf(t1, o1);
                t2 = fmaxf(lo, fmaxf(t2, o2));
                t1 = hi;
            }
            if (col == 0) {
                int p = wv * 32 + mt * 16 + g * 4 + r;
                sCand[p * 2]     = 511 - (int)(__float_as_uint(t1) & 511u);
                sCand[p * 2 + 1] = 511 - (int)(__float_as_uint(t2) & 511u);
            }
        }
    __syncthreads();

    // ---- exact fp32 rescore of both candidates (2 threads per point) ----
    int p = t & 127, wc = t >> 7;
    int c = sCand[p * 2 + wc];
    const v4f* erow = (const v4f*)(embed + c * 64);
    float dot = 0.f;
    #pragma unroll
    for (int plane = 0; plane < 16; ++plane) {
        v4f xq = *(const v4f*)&sX[plane * PS + p * 4];
        v4f e4 = erow[plane];
        dot = fmaf(xq[0], e4[0], dot);
        dot = fmaf(xq[1], e4[1], dot);
        dot = fmaf(xq[2], e4[2], dot);
        dot = fmaf(xq[3], e4[3], dot);
    }
    float sx = fmaf(2.f, dot, -sEE[c]);
    sRes[t] = sx;
    __syncthreads();
    float so = sRes[t ^ 128];
    int co = sCand[p * 2 + (1 - wc)];
    bool win = (sx > so) || (sx == so && c < co);

    // winner: ids + quantized + commit contribution
    float cl = 0.f;
    if (win) {
        int h = (h2 << 1) + (p >> 6), w = p & 63;
        ws_ids[b * HW + h2 * 128 + p] = c;                 // natural order
        out_ids[b * HW + w * 64 + h] = (float)c;           // (b,w,h) quirk
        float* qg = out_q + (size_t)b * (EMB * HW) + h2 * 128 + p;
        #pragma unroll
        for (int plane = 0; plane < 16; ++plane) {
            v4f xq = *(const v4f*)&sX[plane * PS + p * 4];
            v4f e4 = erow[plane];
            #pragma unroll
            for (int v = 0; v < 4; ++v) {
                int ch = plane * 4 + v;
                qg[(size_t)ch * HW] = e4[v];
                float d = xq[v] - e4[v];
                cl = fmaf(d, d, cl);
            }
        }
    }
    #pragma unroll
    for (int off = 32; off > 0; off >>= 1) cl += __shfl_down(cl, off);
    if ((t & 63) == 0) cred[t >> 6] = cl;
    __syncthreads();
    if (t == 0)
        unsafeAtomicAdd(&ws[WS_COMMIT], (cred[0] + cred[1]) + (cred[2] + cred[3]));
}

// ------------------------------------------------- stats: esum + counts
// 1024 blocks = (b, 32 groups of 2 channels). LDS histogram in FIXED-POINT
// uint via native non-returning ds_add_u32 (float LDS atomics stall: R11).
__global__ __launch_bounds__(256) void vq_stats(
    const float* __restrict__ input, const int* __restrict__ ws_ids,
    float* __restrict__ ws) {
    __shared__ uint es[2 * 520];
    __shared__ uint cnt_s[DICT];

    int t = threadIdx.x;
    int bc = blockIdx.x;
    int b = bc >> 5, cg = bc & 31;

    #pragma unroll
    for (int i = t; i < 2 * 520; i += 256) es[i] = 0u;
    if (cg == 0)
        for (int i = t; i < DICT; i += 256) cnt_s[i] = 0u;

    const int* idg = ws_ids + b * HW;
    int4 idv[4];
    #pragma unroll
    for (int it = 0; it < 4; ++it)
        idv[it] = *(const int4*)(idg + (t + it * 256) * 4);
    __syncthreads();

    #pragma unroll
    for (int chl = 0; chl < 2; ++chl) {
        const float* xg = input + (size_t)b * (EMB * HW) + (size_t)(cg * 2 + chl) * HW;
        uint* esr = es + chl * 520;
        #pragma unroll
        for (int it = 0; it < 4; ++it) {
            v4f x = *(const v4f*)(xg + (t + it * 256) * 4);
            atomicAdd(&esr[idv[it].x], (uint)__float2int_rn(x.x * ESCALE));
            atomicAdd(&esr[idv[it].y], (uint)__float2int_rn(x.y * ESCALE));
            atomicAdd(&esr[idv[it].z], (uint)__float2int_rn(x.z * ESCALE));
            atomicAdd(&esr[idv[it].w], (uint)__float2int_rn(x.w * ESCALE));
        }
    }
    if (cg == 0) {
        #pragma unroll
        for (int it = 0; it < 4; ++it) {
            atomicAdd(&cnt_s[idv[it].x], 1u);
            atomicAdd(&cnt_s[idv[it].y], 1u);
            atomicAdd(&cnt_s[idv[it].z], 1u);
            atomicAdd(&cnt_s[idv[it].w], 1u);
        }
    }
    __syncthreads();

    #pragma unroll
    for (int i = t; i < 2 * DICT; i += 256) {
        int chl = i >> 9, j = i & 511;
        int v = (int)es[chl * 520 + j];
        if (v != 0)
            unsafeAtomicAdd(&ws[WS_ESUM + (cg * 2 + chl) * DICT + j],
                            (float)v * EINV);
    }
    if (cg == 0)
        for (int i = t; i < DICT; i += 256) {
            uint c = cnt_s[i];
            if (c != 0u) unsafeAtomicAdd(&ws[WS_COUNTS + i], (float)c);
        }
}

// ---------------------------------------------------- finalize (fused fin1+fin2)
// 128 blocks x 256; each block redundantly reduces n (deterministic).
__global__ __launch_bounds__(256) void vq_fin(
    const float* __restrict__ embed_avg, const float* __restrict__ cluster_size,
    const float* __restrict__ ws, float* __restrict__ out_embed,
    float* __restrict__ out_cs, float* __restrict__ out_avg,
    float* __restrict__ out_loss) {
    __shared__ float red[256];
    int t = threadIdx.x, blk = blockIdx.x;

    float ncs0 = cluster_size[t] * MOM + ws[WS_COUNTS + t] * OMOM;
    float ncs1 = cluster_size[t + 256] * MOM + ws[WS_COUNTS + t + 256] * OMOM;
    if (blk == 0) {
        out_cs[t] = ncs0;
        out_cs[t + 256] = ncs1;
        if (t == 0)
            out_loss[0] = ws[WS_COMMIT] * (1.0f / (float)((size_t)NPTS * EMB));
    }
    red[t] = ncs0 + ncs1;
    __syncthreads();
    #pragma unroll
    for (int off = 128; off > 0; off >>= 1) {
        if (t < off) red[t] += red[t + off];
        __syncthreads();
    }
    float n = red[0];

    int idx = blk * 256 + t;          // idx = ch*512 + d
    int ch = idx >> 9, d = idx & 511;
    float avg = embed_avg[idx] * MOM + ws[WS_ESUM + idx] * OMOM;
    out_avg[idx] = avg;
    float ncs = cluster_size[d] * MOM + ws[WS_COUNTS + d] * OMOM;
    float cs = n * (ncs + EPSV) / (n + (float)DICT * EPSV);
    out_embed[d * EMB + ch] = avg / cs;
}

extern "C" void kernel_launch(void* const* d_in, const int* in_sizes, int n_in,
                              void* d_out, int out_size, void* d_ws, size_t ws_size,
                              hipStream_t stream) {
    const float* input        = (const float*)d_in[0];
    const float* embed        = (const float*)d_in[1];
    const float* cluster_size = (const float*)d_in[2];
    const float* embed_avg    = (const float*)d_in[3];

    float* out   = (float*)d_out;
    float* q     = out;                         // 8388608
    float* loss  = out + 8388608;               // 1
    float* ids   = out + 8388609;               // 131072
    float* oemb  = out + 8519681;               // 32768
    float* ocs   = out + 8552449;               // 512
    float* oavg  = out + 8552961;               // 32768
    float* ws    = (float*)d_ws;

    vq_prep  <<<32, 256, 0, stream>>>(embed, ws, (uint*)(ws + WS_EHG), ws + WS_EE);
    vq_argmax<<<1024, 256, 0, stream>>>(input, (const uint*)(ws + WS_EHG),
                                        ws + WS_EE, embed, q, ids,
                                        (int*)(ws + WS_IDS), ws);
    vq_stats <<<1024, 256, 0, stream>>>(input, (const int*)(ws + WS_IDS), ws);
    vq_fin   <<<128, 256, 0, stream>>>(embed_avg, cluster_size, ws, oemb, ocs,
                                       oavg, loss);
}